// Round 5
// baseline (72.690 us; speedup 1.0000x reference)
//
#include <hip/hip_runtime.h>
#include <hip/hip_bf16.h>

typedef __attribute__((ext_vector_type(8))) short bf16x8;
typedef __attribute__((ext_vector_type(4))) float f32x4;
typedef __attribute__((ext_vector_type(4))) int i32x4;

// RNE round two fp32 -> packed bf16 pair (elem a = low half)
__device__ inline unsigned int pack_bf2(float a, float b) {
    unsigned int ua = __builtin_bit_cast(unsigned int, a);
    unsigned int ub = __builtin_bit_cast(unsigned int, b);
    ua = (ua + 0x7fffu + ((ua >> 16) & 1u)) >> 16;
    ub = (ub + 0x7fffu + ((ub >> 16) & 1u)) >> 16;
    return (ub << 16) | (ua & 0xffffu);
}

// ---------------------------------------------------------------------------
// Kernel 1: repack conv_w [K=768][N=256] fp32 -> bf16 in MFMA B-fragment order.
// Bpack frag index t = (nt*24 + ksg)*64 + lane, 8 bf16 per t (one int4).
// Fragment semantics: B[k][n], k = ksg*32 + (lane>>4)*8 + j, n = nt*16 + (lane&15).
// ---------------------------------------------------------------------------
__global__ void pack_w_kernel(const float* __restrict__ conv_w, i32x4* __restrict__ bpack) {
    int t = blockIdx.x * 256 + threadIdx.x;       // 0 .. 24575
    int lane = t & 63;
    int g = t >> 6;                                // nt*24 + ksg
    int nt = g / 24, ks = g - nt * 24;
    int k0 = ks * 32 + ((lane >> 4) << 3);
    int n  = nt * 16 + (lane & 15);
    const float* src = conv_w + (size_t)k0 * 256 + n;
    float v[8];
#pragma unroll
    for (int j = 0; j < 8; ++j) v[j] = src[(size_t)j * 256];
    i32x4 o;
    o.x = pack_bf2(v[0], v[1]);
    o.y = pack_bf2(v[2], v[3]);
    o.z = pack_bf2(v[4], v[5]);
    o.w = pack_bf2(v[6], v[7]);
    bpack[t] = o;
}

// ---------------------------------------------------------------------------
// Kernel 2: conv stem as bf16 MFMA patch-GEMM.  (R5: B single-buffered,
// loaded per-chunk AFTER the barrier and BEFORE image prefetch so the MFMA
// vmcnt wait doesn't drain the image loads; -24 VGPR vs R4, est ~100 < 128.)
// Block: 512 thr = 8 waves (2M x 4N). Tile M=64 x N=128; wave M=32 x N=32.
// K-chunk=96 staged to LDS bf16 (stride 104), double-buffered. Grid 512.
// ---------------------------------------------------------------------------
__global__ __launch_bounds__(512, 4) void conv_kernel(
    const float* __restrict__ images,
    const i32x4* __restrict__ bpack,
    const float* __restrict__ conv_b,
    float* __restrict__ feat) {
    __shared__ short ldsA[2][64 * 104];   // [buf][patch 0..63][k 0..95, stride 104]

    const int tid  = threadIdx.x;
    const int lane = tid & 63;
    const int w    = tid >> 6;        // wave 0..7
    const int l15  = lane & 15;
    const int lg   = lane >> 4;       // 0..3
    const int wr   = w >> 2;          // wave M-row 0..1
    const int wc   = w & 3;           // wave N-col 0..3

    // XCD swizzle: consecutive works (nhalf pair of same strips) share an XCD
    const int work  = (blockIdx.x & 7) * 64 + (blockIdx.x >> 3);
    const int mi    = work >> 1;      // strip pair index (M-block of 64)
    const int nhalf = work & 1;

    // staging coords: strip ss (0..1), row-in-chunk sr (0..1), col tc (0..127)
    const int ss = tid >> 8;
    const int sr = (tid >> 7) & 1;
    const int tc = tid & 127;
    const int gstrip = 2 * mi + ss;
    const float* rowbase = images
        + (size_t)(((gstrip >> 5) << 9) + ((gstrip & 31) << 4) + sr) * 1536 + tc * 4;

    // staging LDS indices (3 writes/thread), precomputed
    int widx[3];
#pragma unroll
    for (int p = 0; p < 3; ++p) {
        int fp = tc + (p << 7);               // float4 index in row [0,384)
        int j = (fp * 1366) >> 14;            // fp/12 exact for fp<384
        int q = fp - 12 * j;
        widx[p] = (ss * 32 + j) * 104 + sr * 48 + (q << 2);
    }

    float bias[2];
#pragma unroll
    for (int sub = 0; sub < 2; ++sub)
        bias[sub] = conv_b[nhalf * 128 + wc * 32 + sub * 16 + l15];

    // B fragment base: nt = nhalf*8 + wc*2 + sub, frag offset (sub*24 + ksg)*64
    const i32x4* bp = bpack + (size_t)((nhalf * 8 + wc * 2) * 24) * 64 + lane;

    f32x4 acc[2][2] = {};
    f32x4 st[3];

    // ---- prologue: stage chunk 0 ----
#pragma unroll
    for (int p = 0; p < 3; ++p) st[p] = *(const f32x4*)(rowbase + p * 512);
#pragma unroll
    for (int p = 0; p < 3; ++p) {
        int2 v;
        v.x = pack_bf2(st[p].x, st[p].y);
        v.y = pack_bf2(st[p].z, st[p].w);
        *(int2*)(&ldsA[0][widx[p]]) = v;
    }
    __syncthreads();

#pragma unroll
    for (int c = 0; c < 8; ++c) {
        // B for THIS chunk: issued first so the MFMA wait leaves image loads in flight
        i32x4 Bc[2][3];
#pragma unroll
        for (int sub = 0; sub < 2; ++sub)
#pragma unroll
        for (int s = 0; s < 3; ++s)
            Bc[sub][s] = bp[(size_t)(sub * 24 + c * 3 + s) * 64];
        // image prefetch for chunk c+1 (consumed after the compute phase)
        if (c < 7) {
            const float* rb = rowbase + (size_t)(c + 1) * 3072;
#pragma unroll
            for (int p = 0; p < 3; ++p) st[p] = *(const f32x4*)(rb + p * 512);
        }
        // compute chunk c from LDS buf (c&1)
        const short* bufA = &ldsA[c & 1][0];
#pragma unroll
        for (int s = 0; s < 3; ++s) {
            bf16x8 aF0 = *(const bf16x8*)(&bufA[(wr * 32 + l15) * 104 + s * 32 + lg * 8]);
            bf16x8 aF1 = *(const bf16x8*)(&bufA[(wr * 32 + 16 + l15) * 104 + s * 32 + lg * 8]);
#pragma unroll
            for (int sub = 0; sub < 2; ++sub) {
                bf16x8 bF = __builtin_bit_cast(bf16x8, Bc[sub][s]);
                acc[0][sub] = __builtin_amdgcn_mfma_f32_16x16x32_bf16(aF0, bF, acc[0][sub], 0, 0, 0);
                acc[1][sub] = __builtin_amdgcn_mfma_f32_16x16x32_bf16(aF1, bF, acc[1][sub], 0, 0, 0);
            }
        }
        // stage chunk c+1 into other buffer
        if (c < 7) {
            short* dstA = &ldsA[(c + 1) & 1][0];
#pragma unroll
            for (int p = 0; p < 3; ++p) {
                int2 v;
                v.x = pack_bf2(st[p].x, st[p].y);
                v.y = pack_bf2(st[p].z, st[p].w);
                *(int2*)(&dstA[widx[p]]) = v;
            }
        }
        __syncthreads();
    }

    // epilogue: D row in 16-tile = 4*lg + r, col = l15
    const int m0 = mi * 64 + wr * 32;
    const int nc0 = nhalf * 128 + wc * 32;
#pragma unroll
    for (int mt = 0; mt < 2; ++mt)
#pragma unroll
    for (int sub = 0; sub < 2; ++sub)
#pragma unroll
    for (int r = 0; r < 4; ++r) {
        int m = m0 + mt * 16 + lg * 4 + r;
        float v = acc[mt][sub][r] + bias[sub];
        feat[(size_t)m * 256 + nc0 + sub * 16 + l15] = fmaxf(v, 0.f);
    }
}

// ---------------------------------------------------------------------------
// Kernel 3: RoI-align (7x7 bilinear, mean) + mask + dense.  1 block per (b,n).
// FROZEN vs round 4 (decomposition baseline).
// ---------------------------------------------------------------------------
__global__ __launch_bounds__(512) void roi_dense_kernel(
    const float* __restrict__ bboxes,
    const float* __restrict__ feat,
    const float* __restrict__ dense_w,
    const float* __restrict__ dense_b,
    float* __restrict__ out) {
    __shared__ int   offs[4][49];
    __shared__ float wts[4][49];
    __shared__ float part[512];
    __shared__ float objv[256];

    const int bn = blockIdx.x;         // b*16 + n
    const int b  = bn >> 4;
    const int tid = threadIdx.x;

    const float4 box = *(const float4*)(bboxes + (size_t)bn * 4); // ymin,xmin,ymax,xmax
    bool empty = (box.x == -1.f) & (box.y == -1.f) & (box.z == -1.f) & (box.w == -1.f);
    if (empty) {
        if (tid < 256) out[(size_t)bn * 256 + tid] = dense_b[tid];
        return;
    }

    if (tid < 49) {
        int sy = tid / 7, sx = tid - sy * 7;
        float py = (box.x + (box.z - box.x) * ((sy + 0.5f) * (1.0f / 7.0f))) * 32.f - 0.5f;
        float px = (box.y + (box.w - box.y) * ((sx + 0.5f) * (1.0f / 7.0f))) * 32.f - 0.5f;
        float y0f = floorf(py), x0f = floorf(px);
        float wy = py - y0f, wx = px - x0f;
        int y0 = min(max((int)y0f, 0), 31);
        int y1 = min(max((int)y0f + 1, 0), 31);
        int x0 = min(max((int)x0f, 0), 31);
        int x1 = min(max((int)x0f + 1, 0), 31);
        offs[0][tid] = (y0 * 32 + x0) * 256;
        offs[1][tid] = (y0 * 32 + x1) * 256;
        offs[2][tid] = (y1 * 32 + x0) * 256;
        offs[3][tid] = (y1 * 32 + x1) * 256;
        wts[0][tid] = (1.f - wy) * (1.f - wx);
        wts[1][tid] = (1.f - wy) * wx;
        wts[2][tid] = wy * (1.f - wx);
        wts[3][tid] = wy * wx;
    }
    __syncthreads();

    const int c = tid & 255, h = tid >> 8;
    const float* fb = feat + (size_t)b * (1024 * 256) + c;
    float accv = 0.f;
    for (int s = h; s < 49; s += 2) {
        accv += wts[0][s] * fb[offs[0][s]];
        accv += wts[1][s] * fb[offs[1][s]];
        accv += wts[2][s] * fb[offs[2][s]];
        accv += wts[3][s] * fb[offs[3][s]];
    }
    part[tid] = accv;
    __syncthreads();
    if (tid < 256) objv[tid] = (part[tid] + part[tid + 256]) * (1.f / 49.f);
    __syncthreads();

    const float* dwp = dense_w + (size_t)(h * 128) * 256 + c;
    float da = 0.f;
#pragma unroll 8
    for (int cc = 0; cc < 128; ++cc) da += objv[h * 128 + cc] * dwp[(size_t)cc * 256];
    part[tid] = da;
    __syncthreads();
    if (tid < 256) out[(size_t)bn * 256 + tid] = part[tid] + part[tid + 256] + dense_b[tid];
}

extern "C" void kernel_launch(void* const* d_in, const int* in_sizes, int n_in,
                              void* d_out, int out_size, void* d_ws, size_t ws_size,
                              hipStream_t stream) {
    const float* images  = (const float*)d_in[0];   // [16,512,512,3]
    const float* bboxes  = (const float*)d_in[1];   // [16,16,4]
    const float* conv_w  = (const float*)d_in[2];   // [16,16,3,256]
    const float* conv_b  = (const float*)d_in[3];   // [256]
    const float* dense_w = (const float*)d_in[4];   // [256,256]
    const float* dense_b = (const float*)d_in[5];   // [256]
    float* out = (float*)d_out;

    char* ws = (char*)d_ws;
    i32x4* bpack = (i32x4*)ws;                      // 384 KiB (bf16 B fragments)
    float* feat  = (float*)(ws + 512 * 1024);       // 16384*256 fp32 = 16 MiB

    pack_w_kernel<<<96, 256, 0, stream>>>(conv_w, bpack);
    // DECOMPOSITION ROUND: conv launched 3x (idempotent).
    // total = other + 3*conv  ->  delta vs 38.7us bounds conv's warm cost,
    // and the ~55us profiled conv rows displace the 40us fills in top-5,
    // exposing conv's VGPR/MfmaUtil/Occupancy/FETCH counters.
    conv_kernel<<<512, 512, 0, stream>>>(images, bpack, conv_b, feat);
    conv_kernel<<<512, 512, 0, stream>>>(images, bpack, conv_b, feat);
    conv_kernel<<<512, 512, 0, stream>>>(images, bpack, conv_b, feat);
    roi_dense_kernel<<<256, 512, 0, stream>>>(bboxes, feat, dense_w, dense_b, out);
}